// Round 6
// baseline (678.918 us; speedup 1.0000x reference)
//
#include <hip/hip_runtime.h>
#include <hip/hip_bf16.h>
#include <stdint.h>

typedef __attribute__((ext_vector_type(8))) short bf16x8;
typedef __attribute__((ext_vector_type(4))) short short4v;
typedef __attribute__((ext_vector_type(4))) float f32x4;

#define GLOAD16(g, s) __builtin_amdgcn_global_load_lds( \
    (const __attribute__((address_space(1))) void*)(g),  \
    (__attribute__((address_space(3))) void*)(s), 16, 0, 0)

static __device__ __forceinline__ short f2bf(float f) {
  unsigned u = __builtin_bit_cast(unsigned, f);
  u += 0x7fffu + ((u >> 16) & 1u);
  return (short)(u >> 16);
}

static __device__ __forceinline__ f32x4 mfma16(bf16x8 a, bf16x8 b, f32x4 c) {
  return __builtin_amdgcn_mfma_f32_16x16x32_bf16(a, b, c, 0, 0, 0);
}

// ---------------- fp32 -> bf16 convert (plain layout) ----------------
__global__ __launch_bounds__(256) void cvt_bf16(const float* __restrict__ in,
                                                short* __restrict__ out, int n4) {
  int i = blockIdx.x * 256 + threadIdx.x;
  if (i < n4) {
    float4 v = ((const float4*)in)[i];
    short4v o;
    o[0] = f2bf(v.x); o[1] = f2bf(v.y); o[2] = f2bf(v.z); o[3] = f2bf(v.w);
    ((short4v*)out)[i] = o;
  }
}

// W_O [D][DH][H] fp32 -> Wo2 [D][H*DH] bf16 with col c=(i*64+h)
__global__ __launch_bounds__(256) void cvt_wo(const float* __restrict__ in,
                                              short* __restrict__ out) {
  int idx = blockIdx.x * 256 + threadIdx.x;  // 0..1M
  int d = idx >> 10, cc = idx & 1023;
  int i = cc >> 6, h = cc & 63;
  out[idx] = f2bf(in[((size_t)d * 64 + h) * 16 + i]);
}

// ---------------- LayerNorm: fp32 [rows][1024] -> bf16 ----------------
__global__ __launch_bounds__(256) void ln_kernel(const float* __restrict__ x,
                                                 const float* __restrict__ w,
                                                 const float* __restrict__ b,
                                                 short* __restrict__ y) {
  const int row = blockIdx.x, tid = threadIdx.x;
  const int lane = tid & 63, wave = tid >> 6;
  const float4 xv = *(const float4*)&x[(size_t)row * 1024 + tid * 4];
  float s1 = xv.x + xv.y + xv.z + xv.w;
  float s2 = xv.x * xv.x + xv.y * xv.y + xv.z * xv.z + xv.w * xv.w;
#pragma unroll
  for (int off = 1; off < 64; off <<= 1) {
    s1 += __shfl_xor(s1, off);
    s2 += __shfl_xor(s2, off);
  }
  __shared__ float red[8];
  if (lane == 0) { red[wave] = s1; red[4 + wave] = s2; }
  __syncthreads();
  s1 = red[0] + red[1] + red[2] + red[3];
  s2 = red[4] + red[5] + red[6] + red[7];
  const float mu = s1 * (1.0f / 1024.0f);
  const float var = s2 * (1.0f / 1024.0f) - mu * mu;
  const float rs = rsqrtf(var + 1e-5f);
  const float4 wv = *(const float4*)&w[tid * 4];
  const float4 bv = *(const float4*)&b[tid * 4];
  short4v o;
  o[0] = f2bf((xv.x - mu) * rs * wv.x + bv.x);
  o[1] = f2bf((xv.y - mu) * rs * wv.y + bv.y);
  o[2] = f2bf((xv.z - mu) * rs * wv.z + bv.z);
  o[3] = f2bf((xv.w - mu) * rs * wv.w + bv.w);
  *(short4v*)&y[(size_t)row * 1024 + tid * 4] = o;
}

// ---------------- GEMM: C[M,N] = A[M,K] * Bw[N,K]^T, bf16 in fp32 acc --------
template <int MODE>
__global__ __launch_bounds__(256) void gemm_bf16k(
    const short* __restrict__ A, const short* __restrict__ Bw,
    float* __restrict__ outF, short* __restrict__ outB,
    const float* __restrict__ resid, const float* __restrict__ bias,
    int M, int N, int K) {
  __shared__ short As[128 * 64];
  __shared__ short Bs[128 * 64];
  const int tid = threadIdx.x, lane = tid & 63, wave = tid >> 6;
  const int m0 = blockIdx.y * 128, n0 = blockIdx.x * 128;
  const int wm = (wave & 1) * 64, wn = (wave >> 1) * 64;
  const int lr = lane >> 3;        // row within 8-row chunk
  const int lc = (lane & 7) * 8;   // elem col within chunk row
  f32x4 acc[4][4] = {};

  for (int kt = 0; kt < K; kt += 64) {
#pragma unroll
    for (int ch0 = 0; ch0 < 4; ++ch0) {
      const int ch = ch0 * 4 + wave;
      const short* ga = A + (size_t)(m0 + ch * 8 + lr) * K + kt + lc;
      const short* gb = Bw + (size_t)(n0 + ch * 8 + lr) * K + kt + lc;
      GLOAD16(ga, &As[ch * 512]);
      GLOAD16(gb, &Bs[ch * 512]);
    }
    __syncthreads();
#pragma unroll
    for (int kk = 0; kk < 64; kk += 32) {
      bf16x8 af[4], bfr[4];
#pragma unroll
      for (int i2 = 0; i2 < 4; ++i2)
        af[i2] = *(const bf16x8*)&As[(wm + i2 * 16 + (lane & 15)) * 64 + kk + (lane >> 4) * 8];
#pragma unroll
      for (int j2 = 0; j2 < 4; ++j2)
        bfr[j2] = *(const bf16x8*)&Bs[(wn + j2 * 16 + (lane & 15)) * 64 + kk + (lane >> 4) * 8];
#pragma unroll
      for (int i2 = 0; i2 < 4; ++i2)
#pragma unroll
        for (int j2 = 0; j2 < 4; ++j2)
          acc[i2][j2] = mfma16(af[i2], bfr[j2], acc[i2][j2]);
    }
    __syncthreads();
  }

#pragma unroll
  for (int i2 = 0; i2 < 4; ++i2)
#pragma unroll
    for (int j2 = 0; j2 < 4; ++j2)
#pragma unroll
      for (int r = 0; r < 4; ++r) {
        const int m = m0 + wm + i2 * 16 + (lane >> 4) * 4 + r;
        const int n = n0 + wn + j2 * 16 + (lane & 15);
        const float v = acc[i2][j2][r];
        if (MODE == 0) {
          const size_t oi =
              ((size_t)((m >> 11) * 16 + (n >> 6)) * 2048 + (m & 2047)) * 64 + (n & 63);
          outB[oi] = f2bf(v);
        } else if (MODE == 1) {
          outF[(size_t)m * N + n] = resid[(size_t)m * N + n] + v;
        } else if (MODE == 2) {
          const float t2 = v + bias[n];
          outB[(size_t)m * N + n] = f2bf(t2 > 0.0f ? t2 : 0.0f);
        } else {
          outF[(size_t)m * N + n] = resid[(size_t)m * N + n] + v + bias[n];
        }
      }
}

// ---------------- V transpose: [BH][S][64] -> [BH][64][S] ----------------
__global__ __launch_bounds__(256) void transpose_v(const short* __restrict__ V,
                                                   short* __restrict__ Vt) {
  __shared__ short t[64][72];
  const int bi = blockIdx.y;
  const int p0 = blockIdx.x * 64;
  const short* Vh = V + (size_t)bi * 2048 * 64;
  short* Vth = Vt + (size_t)bi * 64 * 2048;
  const int tid = threadIdx.x;
  {
    const int pr = tid >> 2, h0 = (tid & 3) * 16;
    const bf16x8* src = (const bf16x8*)&Vh[(size_t)(p0 + pr) * 64 + h0];
    bf16x8 v0 = src[0], v1 = src[1];
#pragma unroll
    for (int j = 0; j < 8; ++j) { t[pr][h0 + j] = v0[j]; t[pr][h0 + 8 + j] = v1[j]; }
  }
  __syncthreads();
  {
    const int hr = tid >> 2, pq = (tid & 3) * 16;
    bf16x8 o0, o1;
#pragma unroll
    for (int j = 0; j < 8; ++j) { o0[j] = t[pq + j][hr]; o1[j] = t[pq + 8 + j][hr]; }
    *(bf16x8*)&Vth[(size_t)hr * 2048 + p0 + pq] = o0;
    *(bf16x8*)&Vth[(size_t)hr * 2048 + p0 + pq + 8] = o1;
  }
}

// ---------------- attn_flash: (m,l) + z only, NO att stores ----------------
// Block = 32 q-rows, 8 waves = 2 qs x 4 p-chunks. Phase A: partial (m,l) ->
// merge -> write ml[bi][q]={M, 1/L}. Phase B: z partial. Phase C: z merge.
__global__ __launch_bounds__(512, 4) void attn_flash(
    const short* __restrict__ Q, const short* __restrict__ K,
    const short* __restrict__ Vt, float* __restrict__ ml,
    short* __restrict__ zb) {
  // LDS: pbuf [0,8192) 8w x 16x32 bf16 ; mlb [8192,9216) ; zm [0,24576) after sync
  __shared__ __align__(16) char smem[24576];
  const int tid = threadIdx.x, lane = tid & 63, wave = tid >> 6;
  const int g = lane >> 4, c = lane & 15;
  const int qs = wave >> 2, pc = wave & 3;
  const int qt = 63 - (int)blockIdx.x;   // heavy q-tiles dispatch first
  const int bi = blockIdx.y;
  const int b = bi >> 4, hd = bi & 15;
  const size_t hoff = (size_t)bi * 2048 * 64;
  const short* Qh = Q + hoff;
  const short* Kh = K + hoff;
  const short* Vth = Vt + hoff;
  short* zbh = zb + (size_t)b * 2048 * 1024 + hd * 64;

  const int P = qt * 32 + 32;
  const int csz = ((P + 127) >> 7) << 5;
  const int qw = qt * 32 + qs * 16;
  const int p_lo = pc * csz;
  const int p_hi = min(p_lo + csz, P);
  const int clipUp = ((qw + 16 + 31) >> 5) << 5;
  const int clip = min(p_hi, max(p_lo, clipUp));

  short* pbuf = (short*)smem + wave * 512;
  float* mlb  = (float*)(smem + 8192);
  float* zm   = (float*)smem;

  const bf16x8* qp = (const bf16x8*)&Qh[(size_t)(qw + c) * 64];
  const bf16x8 aq0 = qp[g], aq1 = qp[4 + g];

  // ---- phase A: partial (m,l) with K prefetch
  float m4[4], l4[4];
#pragma unroll
  for (int r = 0; r < 4; ++r) { m4[r] = -1e30f; l4[r] = 0.0f; }
  if (p_lo < clip) {
    const bf16x8* kp0 = (const bf16x8*)&Kh[(size_t)(p_lo + c) * 64];
    const bf16x8* kp1 = (const bf16x8*)&Kh[(size_t)(p_lo + 16 + c) * 64];
    bf16x8 ka0 = kp0[g], ka1 = kp0[4 + g], kb0 = kp1[g], kb1 = kp1[4 + g];
    for (int p0 = p_lo; p0 < clip; p0 += 32) {
      f32x4 s0 = {0.0f, 0.0f, 0.0f, 0.0f}, s1 = {0.0f, 0.0f, 0.0f, 0.0f};
      s0 = mfma16(aq0, ka0, s0);
      s0 = mfma16(aq1, ka1, s0);
      s1 = mfma16(aq0, kb0, s1);
      s1 = mfma16(aq1, kb1, s1);
      if (p0 + 32 < clip) {
        const bf16x8* np0 = (const bf16x8*)&Kh[(size_t)(p0 + 32 + c) * 64];
        const bf16x8* np1 = (const bf16x8*)&Kh[(size_t)(p0 + 48 + c) * 64];
        ka0 = np0[g]; ka1 = np0[4 + g]; kb0 = np1[g]; kb1 = np1[4 + g];
      }
#pragma unroll
      for (int r = 0; r < 4; ++r) {
        const int q = qw + g * 4 + r;
        const float v0 = (p0 + c <= q) ? s0[r] * 0.125f : -1e30f;
        const float v1 = (p0 + 16 + c <= q) ? s1[r] * 0.125f : -1e30f;
        const float mn = fmaxf(m4[r], fmaxf(v0, v1));
        l4[r] = l4[r] * __expf(m4[r] - mn) + __expf(v0 - mn) + __expf(v1 - mn);
        m4[r] = mn;
      }
    }
  }
#pragma unroll
  for (int r = 0; r < 4; ++r) {
#pragma unroll
    for (int off = 1; off < 16; off <<= 1) {
      const float mo = __shfl_xor(m4[r], off);
      const float lo = __shfl_xor(l4[r], off);
      const float mn = fmaxf(m4[r], mo);
      l4[r] = l4[r] * __expf(m4[r] - mn) + lo * __expf(mo - mn);
      m4[r] = mn;
    }
  }
  if (c == 0) {
#pragma unroll
    for (int r = 0; r < 4; ++r) {
      mlb[(((qs * 4 + pc) * 16) + g * 4 + r) * 2 + 0] = m4[r];
      mlb[(((qs * 4 + pc) * 16) + g * 4 + r) * 2 + 1] = l4[r];
    }
  }
  __syncthreads();
  float il[4];
#pragma unroll
  for (int r = 0; r < 4; ++r) {
    const int row = g * 4 + r;
    float M = -1e30f;
#pragma unroll
    for (int j = 0; j < 4; ++j)
      M = fmaxf(M, mlb[(((qs * 4 + j) * 16) + row) * 2 + 0]);
    float L = 0.0f;
#pragma unroll
    for (int j = 0; j < 4; ++j) {
      const float mj = mlb[(((qs * 4 + j) * 16) + row) * 2 + 0];
      const float lj = mlb[(((qs * 4 + j) * 16) + row) * 2 + 1];
      L += lj * __expf(mj - M);
    }
    m4[r] = M;
    il[r] = 1.0f / L;
  }
  // publish (M, 1/L) for the att_write kernel
  if (pc == 0 && c == 0) {
#pragma unroll
    for (int r = 0; r < 4; ++r)
      ((float2*)ml)[(size_t)bi * 2048 + qw + g * 4 + r] = make_float2(m4[r], il[r]);
  }

  // ---- phase B: z partial over [p_lo, clip), no global stores
  f32x4 zacc[4] = {};
  if (p_lo < clip) {
    const bf16x8* kp0 = (const bf16x8*)&Kh[(size_t)(p_lo + c) * 64];
    const bf16x8* kp1 = (const bf16x8*)&Kh[(size_t)(p_lo + 16 + c) * 64];
    bf16x8 ka0 = kp0[g], ka1 = kp0[4 + g], kb0 = kp1[g], kb1 = kp1[4 + g];
    for (int p0 = p_lo; p0 < clip; p0 += 32) {
      f32x4 s0 = {0.0f, 0.0f, 0.0f, 0.0f}, s1 = {0.0f, 0.0f, 0.0f, 0.0f};
      s0 = mfma16(aq0, ka0, s0);
      s0 = mfma16(aq1, ka1, s0);
      s1 = mfma16(aq0, kb0, s1);
      s1 = mfma16(aq1, kb1, s1);
      const bf16x8 bv0 = *(const bf16x8*)&Vth[(size_t)(0 * 16 + c) * 2048 + p0 + g * 8];
      const bf16x8 bv1 = *(const bf16x8*)&Vth[(size_t)(1 * 16 + c) * 2048 + p0 + g * 8];
      const bf16x8 bv2 = *(const bf16x8*)&Vth[(size_t)(2 * 16 + c) * 2048 + p0 + g * 8];
      const bf16x8 bv3 = *(const bf16x8*)&Vth[(size_t)(3 * 16 + c) * 2048 + p0 + g * 8];
      if (p0 + 32 < clip) {
        const bf16x8* np0 = (const bf16x8*)&Kh[(size_t)(p0 + 32 + c) * 64];
        const bf16x8* np1 = (const bf16x8*)&Kh[(size_t)(p0 + 48 + c) * 64];
        ka0 = np0[g]; ka1 = np0[4 + g]; kb0 = np1[g]; kb1 = np1[4 + g];
      }
#pragma unroll
      for (int f = 0; f < 2; ++f) {
        const f32x4& ss = f ? s1 : s0;
#pragma unroll
        for (int r = 0; r < 4; ++r) {
          const int q = qw + g * 4 + r, p = p0 + f * 16 + c;
          const float e = (p <= q) ? __expf(ss[r] * 0.125f - m4[r]) * il[r] : 0.0f;
          pbuf[(g * 4 + r) * 32 + f * 16 + c] = f2bf(e);
        }
      }
      const bf16x8 pa = *(const bf16x8*)&pbuf[c * 32 + g * 8];
      zacc[0] = mfma16(pa, bv0, zacc[0]);
      zacc[1] = mfma16(pa, bv1, zacc[1]);
      zacc[2] = mfma16(pa, bv2, zacc[2]);
      zacc[3] = mfma16(pa, bv3, zacc[3]);
    }
  }

  // ---- phase C: merge z partials across the 4 p-chunks
  __syncthreads();  // pbuf dead in all waves; zm reuses its space
  if (pc != 0) {
#pragma unroll
    for (int hb2 = 0; hb2 < 4; ++hb2)
#pragma unroll
      for (int r = 0; r < 4; ++r)
        zm[(((qs * 3 + (pc - 1)) * 16) + g * 4 + r) * 64 + hb2 * 16 + c] = zacc[hb2][r];
  }
  __syncthreads();
  if (pc == 0) {
#pragma unroll
    for (int hb2 = 0; hb2 < 4; ++hb2)
#pragma unroll
      for (int r = 0; r < 4; ++r) {
        float z = zacc[hb2][r];
#pragma unroll
        for (int j = 0; j < 3; ++j)
          z += zm[(((qs * 3 + j) * 16) + g * 4 + r) * 64 + hb2 * 16 + c];
        zbh[(size_t)(qw + g * 4 + r) * 1024 + hb2 * 16 + c] = f2bf(z);
      }
  }
}

// ---------------- att_write: materialize att, massively parallel -----------
// Grid (64 qtiles of 32) x (8 ptiles of 256) x (32 heads) = 16384 blocks.
// 4 waves = 2 q-subs x 2 p-halves; each wave: 16 q-rows x 128 p (4 iters).
// No barriers, per-wave LDS staging, coalesced nt stores. Zero strips skip
// compute entirely. Longest serial chain: 4 iterations -> TLP-hidden.
__global__ __launch_bounds__(256) void att_write(
    const short* __restrict__ Q, const short* __restrict__ K,
    const float* __restrict__ ml, float* __restrict__ att) {
  __shared__ float fbuf_s[4][16 * 36];
  const int tid = threadIdx.x, lane = tid & 63, wave = tid >> 6;
  const int g = lane >> 4, c = lane & 15;
  const int qt = blockIdx.x, pt = blockIdx.y, bi = blockIdx.z;
  const int qs = wave >> 1, ph = wave & 1;
  const int qw = qt * 32 + qs * 16;
  const int pb = pt * 256 + ph * 128;
  float* atth = att + (size_t)bi * 2048 * 2048;
  const int r0 = lane >> 3, c4 = (lane & 7) * 4;

  if (pb > qw + 15) {  // strip entirely above the diagonal: pure zeros
    const f32x4 zf = {0.0f, 0.0f, 0.0f, 0.0f};
#pragma unroll
    for (int j = 0; j < 4; ++j) {
      __builtin_nontemporal_store(zf, (f32x4*)&atth[(size_t)(qw + r0) * 2048 + pb + j * 32 + c4]);
      __builtin_nontemporal_store(zf, (f32x4*)&atth[(size_t)(qw + 8 + r0) * 2048 + pb + j * 32 + c4]);
    }
    return;
  }

  const size_t hoff = (size_t)bi * 2048 * 64;
  const short* Qh = Q + hoff;
  const short* Kh = K + hoff;
  const bf16x8* qp = (const bf16x8*)&Qh[(size_t)(qw + c) * 64];
  const bf16x8 aq0 = qp[g], aq1 = qp[4 + g];
  float m4[4], il[4];
#pragma unroll
  for (int r = 0; r < 4; ++r) {
    const float2 t = ((const float2*)ml)[(size_t)bi * 2048 + qw + g * 4 + r];
    m4[r] = t.x; il[r] = t.y;
  }
  float* fbuf = fbuf_s[wave];
  for (int p0 = pb; p0 < pb + 128; p0 += 32) {
    const bf16x8* kp0 = (const bf16x8*)&Kh[(size_t)(p0 + c) * 64];
    const bf16x8* kp1 = (const bf16x8*)&Kh[(size_t)(p0 + 16 + c) * 64];
    f32x4 s0 = {0.0f, 0.0f, 0.0f, 0.0f}, s1 = {0.0f, 0.0f, 0.0f, 0.0f};
    s0 = mfma16(aq0, kp0[g], s0);
    s0 = mfma16(aq1, kp0[4 + g], s0);
    s1 = mfma16(aq0, kp1[g], s1);
    s1 = mfma16(aq1, kp1[4 + g], s1);
#pragma unroll
    for (int f = 0; f < 2; ++f) {
      const f32x4& ss = f ? s1 : s0;
#pragma unroll
      for (int r = 0; r < 4; ++r) {
        const int q = qw + g * 4 + r, p = p0 + f * 16 + c;
        const float e = (p <= q) ? __expf(ss[r] * 0.125f - m4[r]) * il[r] : 0.0f;
        fbuf[(g * 4 + r) * 36 + f * 16 + c] = e;
      }
    }
    const f32x4 v0 = *(const f32x4*)&fbuf[r0 * 36 + c4];
    const f32x4 v1 = *(const f32x4*)&fbuf[(8 + r0) * 36 + c4];
    __builtin_nontemporal_store(v0, (f32x4*)&atth[(size_t)(qw + r0) * 2048 + p0 + c4]);
    __builtin_nontemporal_store(v1, (f32x4*)&atth[(size_t)(qw + 8 + r0) * 2048 + p0 + c4]);
  }
}

// ---------------- launch ----------------
extern "C" void kernel_launch(void* const* d_in, const int* in_sizes, int n_in,
                              void* d_out, int out_size, void* d_ws, size_t ws_size,
                              hipStream_t stream) {
  (void)in_sizes; (void)n_in; (void)out_size; (void)ws_size;
  const float* x    = (const float*)d_in[0];
  const float* WQ   = (const float*)d_in[1];
  const float* WK   = (const float*)d_in[2];
  const float* WV   = (const float*)d_in[3];
  const float* WO   = (const float*)d_in[4];
  const float* lnaw = (const float*)d_in[5];
  const float* lnab = (const float*)d_in[6];
  const float* lnmw = (const float*)d_in[7];
  const float* lnmb = (const float*)d_in[8];
  const float* w1   = (const float*)d_in[9];
  const float* b1   = (const float*)d_in[10];
  const float* w2   = (const float*)d_in[11];
  const float* b2   = (const float*)d_in[12];

  char* ws = (char*)d_ws;
  const size_t MB = 1024 * 1024;
  short* Wqb  = (short*)(ws + 0 * MB);   // 2MB
  short* Wkb  = (short*)(ws + 2 * MB);   // 2MB
  short* Wvb  = (short*)(ws + 4 * MB);   // 2MB
  short* Wob  = (short*)(ws + 6 * MB);   // 2MB
  short* w1b  = (short*)(ws + 8 * MB);   // 8MB
  short* w2b  = (short*)(ws + 16 * MB);  // 8MB
  short* yb   = (short*)(ws + 24 * MB);  // 8MB (LN1 out; reused for LN2 out)
  short* Qb   = (short*)(ws + 32 * MB);  // 8MB
  short* Kb   = (short*)(ws + 40 * MB);  // 8MB
  short* Vb   = (short*)(ws + 48 * MB);  // 8MB
  short* Vtb  = (short*)(ws + 56 * MB);  // 8MB
  short* zbuf = (short*)(ws + 64 * MB);  // 8MB
  float* x1   = (float*)(ws + 72 * MB);  // 16MB (written AFTER att_write)
  float* mlw  = (float*)(ws + 72 * MB);  // 512KB, overlaps x1: ml is consumed
                                         // by att_write BEFORE gemm<1> writes
                                         // x1 (stream-ordered) — safe reuse
  short* hb   = (short*)(ws + 32 * MB);  // 32MB, reuses Q/K/V/Vt (dead by MLP1)

  float* outx = (float*)d_out;
  float* att  = outx + (size_t)2 * 2048 * 1024;  // output 1 region

  // weight converts (fp32 -> bf16)
  cvt_bf16<<<dim3(1024), dim3(256), 0, stream>>>(WQ, Wqb, 262144);
  cvt_bf16<<<dim3(1024), dim3(256), 0, stream>>>(WK, Wkb, 262144);
  cvt_bf16<<<dim3(1024), dim3(256), 0, stream>>>(WV, Wvb, 262144);
  cvt_wo<<<dim3(4096), dim3(256), 0, stream>>>(WO, Wob);
  cvt_bf16<<<dim3(4096), dim3(256), 0, stream>>>(w1, w1b, 1048576);
  cvt_bf16<<<dim3(4096), dim3(256), 0, stream>>>(w2, w2b, 1048576);

  // LN1
  ln_kernel<<<dim3(4096), dim3(256), 0, stream>>>(x, lnaw, lnab, yb);

  // QKV projections (scatter to [B,H,S,DH])
  gemm_bf16k<0><<<dim3(8, 32), dim3(256), 0, stream>>>(yb, Wqb, nullptr, Qb, nullptr, nullptr, 4096, 1024, 1024);
  gemm_bf16k<0><<<dim3(8, 32), dim3(256), 0, stream>>>(yb, Wkb, nullptr, Kb, nullptr, nullptr, 4096, 1024, 1024);
  gemm_bf16k<0><<<dim3(8, 32), dim3(256), 0, stream>>>(yb, Wvb, nullptr, Vb, nullptr, nullptr, 4096, 1024, 1024);

  // V transpose for PV B-operand
  transpose_v<<<dim3(32, 32), dim3(256), 0, stream>>>(Vb, Vtb);

  // attention stats + z (no att materialization)
  attn_flash<<<dim3(64, 32), dim3(512), 0, stream>>>(Qb, Kb, Vtb, mlw, zbuf);

  // att materialization (embarrassingly parallel, store-BW-bound)
  att_write<<<dim3(64, 8, 32), dim3(256), 0, stream>>>(Qb, Kb, mlw, att);

  // output projection + residual -> x1 (fp32)
  gemm_bf16k<1><<<dim3(8, 32), dim3(256), 0, stream>>>(zbuf, Wob, x1, nullptr, x, nullptr, 4096, 1024, 1024);

  // LN2
  ln_kernel<<<dim3(4096), dim3(256), 0, stream>>>(x1, lnmw, lnmb, yb);

  // MLP
  gemm_bf16k<2><<<dim3(32, 32), dim3(256), 0, stream>>>(yb, w1b, nullptr, hb, nullptr, b1, 4096, 4096, 1024);
  gemm_bf16k<3><<<dim3(8, 32), dim3(256), 0, stream>>>(hb, w2b, outx, nullptr, x1, b2, 4096, 1024, 4096);
}

// Round 7
// 567.479 us; speedup vs baseline: 1.1964x; 1.1964x over previous
//
#include <hip/hip_runtime.h>
#include <hip/hip_bf16.h>
#include <stdint.h>

typedef __attribute__((ext_vector_type(8))) short bf16x8;
typedef __attribute__((ext_vector_type(4))) short short4v;
typedef __attribute__((ext_vector_type(4))) float f32x4;

#define GLOAD16(g, s) __builtin_amdgcn_global_load_lds( \
    (const __attribute__((address_space(1))) void*)(g),  \
    (__attribute__((address_space(3))) void*)(s), 16, 0, 0)

static __device__ __forceinline__ short f2bf(float f) {
  unsigned u = __builtin_bit_cast(unsigned, f);
  u += 0x7fffu + ((u >> 16) & 1u);
  return (short)(u >> 16);
}

static __device__ __forceinline__ f32x4 mfma16(bf16x8 a, bf16x8 b, f32x4 c) {
  return __builtin_amdgcn_mfma_f32_16x16x32_bf16(a, b, c, 0, 0, 0);
}

// ---------------- fp32 -> bf16 convert (plain layout) ----------------
__global__ __launch_bounds__(256) void cvt_bf16(const float* __restrict__ in,
                                                short* __restrict__ out, int n4) {
  int i = blockIdx.x * 256 + threadIdx.x;
  if (i < n4) {
    float4 v = ((const float4*)in)[i];
    short4v o;
    o[0] = f2bf(v.x); o[1] = f2bf(v.y); o[2] = f2bf(v.z); o[3] = f2bf(v.w);
    ((short4v*)out)[i] = o;
  }
}

// W_O [D][DH][H] fp32 -> Wo2 [D][H*DH] bf16 with col c=(i*64+h)
__global__ __launch_bounds__(256) void cvt_wo(const float* __restrict__ in,
                                              short* __restrict__ out) {
  int idx = blockIdx.x * 256 + threadIdx.x;  // 0..1M
  int d = idx >> 10, cc = idx & 1023;
  int i = cc >> 6, h = cc & 63;
  out[idx] = f2bf(in[((size_t)d * 64 + h) * 16 + i]);
}

// ---------------- LayerNorm: fp32 [rows][1024] -> bf16 ----------------
__global__ __launch_bounds__(256) void ln_kernel(const float* __restrict__ x,
                                                 const float* __restrict__ w,
                                                 const float* __restrict__ b,
                                                 short* __restrict__ y) {
  const int row = blockIdx.x, tid = threadIdx.x;
  const int lane = tid & 63, wave = tid >> 6;
  const float4 xv = *(const float4*)&x[(size_t)row * 1024 + tid * 4];
  float s1 = xv.x + xv.y + xv.z + xv.w;
  float s2 = xv.x * xv.x + xv.y * xv.y + xv.z * xv.z + xv.w * xv.w;
#pragma unroll
  for (int off = 1; off < 64; off <<= 1) {
    s1 += __shfl_xor(s1, off);
    s2 += __shfl_xor(s2, off);
  }
  __shared__ float red[8];
  if (lane == 0) { red[wave] = s1; red[4 + wave] = s2; }
  __syncthreads();
  s1 = red[0] + red[1] + red[2] + red[3];
  s2 = red[4] + red[5] + red[6] + red[7];
  const float mu = s1 * (1.0f / 1024.0f);
  const float var = s2 * (1.0f / 1024.0f) - mu * mu;
  const float rs = rsqrtf(var + 1e-5f);
  const float4 wv = *(const float4*)&w[tid * 4];
  const float4 bv = *(const float4*)&b[tid * 4];
  short4v o;
  o[0] = f2bf((xv.x - mu) * rs * wv.x + bv.x);
  o[1] = f2bf((xv.y - mu) * rs * wv.y + bv.y);
  o[2] = f2bf((xv.z - mu) * rs * wv.z + bv.z);
  o[3] = f2bf((xv.w - mu) * rs * wv.w + bv.w);
  *(short4v*)&y[(size_t)row * 1024 + tid * 4] = o;
}

// ---------------- GEMM: C[M,N] = A[M,K] * Bw[N,K]^T, bf16 in fp32 acc --------
template <int MODE>
__global__ __launch_bounds__(256) void gemm_bf16k(
    const short* __restrict__ A, const short* __restrict__ Bw,
    float* __restrict__ outF, short* __restrict__ outB,
    const float* __restrict__ resid, const float* __restrict__ bias,
    int M, int N, int K) {
  __shared__ short As[128 * 64];
  __shared__ short Bs[128 * 64];
  const int tid = threadIdx.x, lane = tid & 63, wave = tid >> 6;
  const int m0 = blockIdx.y * 128, n0 = blockIdx.x * 128;
  const int wm = (wave & 1) * 64, wn = (wave >> 1) * 64;
  const int lr = lane >> 3;        // row within 8-row chunk
  const int lc = (lane & 7) * 8;   // elem col within chunk row
  f32x4 acc[4][4] = {};

  for (int kt = 0; kt < K; kt += 64) {
#pragma unroll
    for (int ch0 = 0; ch0 < 4; ++ch0) {
      const int ch = ch0 * 4 + wave;
      const short* ga = A + (size_t)(m0 + ch * 8 + lr) * K + kt + lc;
      const short* gb = Bw + (size_t)(n0 + ch * 8 + lr) * K + kt + lc;
      GLOAD16(ga, &As[ch * 512]);
      GLOAD16(gb, &Bs[ch * 512]);
    }
    __syncthreads();
#pragma unroll
    for (int kk = 0; kk < 64; kk += 32) {
      bf16x8 af[4], bfr[4];
#pragma unroll
      for (int i2 = 0; i2 < 4; ++i2)
        af[i2] = *(const bf16x8*)&As[(wm + i2 * 16 + (lane & 15)) * 64 + kk + (lane >> 4) * 8];
#pragma unroll
      for (int j2 = 0; j2 < 4; ++j2)
        bfr[j2] = *(const bf16x8*)&Bs[(wn + j2 * 16 + (lane & 15)) * 64 + kk + (lane >> 4) * 8];
#pragma unroll
      for (int i2 = 0; i2 < 4; ++i2)
#pragma unroll
        for (int j2 = 0; j2 < 4; ++j2)
          acc[i2][j2] = mfma16(af[i2], bfr[j2], acc[i2][j2]);
    }
    __syncthreads();
  }

#pragma unroll
  for (int i2 = 0; i2 < 4; ++i2)
#pragma unroll
    for (int j2 = 0; j2 < 4; ++j2)
#pragma unroll
      for (int r = 0; r < 4; ++r) {
        const int m = m0 + wm + i2 * 16 + (lane >> 4) * 4 + r;
        const int n = n0 + wn + j2 * 16 + (lane & 15);
        const float v = acc[i2][j2][r];
        if (MODE == 0) {
          const size_t oi =
              ((size_t)((m >> 11) * 16 + (n >> 6)) * 2048 + (m & 2047)) * 64 + (n & 63);
          outB[oi] = f2bf(v);
        } else if (MODE == 1) {
          outF[(size_t)m * N + n] = resid[(size_t)m * N + n] + v;
        } else if (MODE == 2) {
          const float t2 = v + bias[n];
          outB[(size_t)m * N + n] = f2bf(t2 > 0.0f ? t2 : 0.0f);
        } else {
          outF[(size_t)m * N + n] = resid[(size_t)m * N + n] + v + bias[n];
        }
      }
}

// ---------------- V transpose: [BH][S][64] -> [BH][64][S] ----------------
__global__ __launch_bounds__(256) void transpose_v(const short* __restrict__ V,
                                                   short* __restrict__ Vt) {
  __shared__ short t[64][72];
  const int bi = blockIdx.y;
  const int p0 = blockIdx.x * 64;
  const short* Vh = V + (size_t)bi * 2048 * 64;
  short* Vth = Vt + (size_t)bi * 64 * 2048;
  const int tid = threadIdx.x;
  {
    const int pr = tid >> 2, h0 = (tid & 3) * 16;
    const bf16x8* src = (const bf16x8*)&Vh[(size_t)(p0 + pr) * 64 + h0];
    bf16x8 v0 = src[0], v1 = src[1];
#pragma unroll
    for (int j = 0; j < 8; ++j) { t[pr][h0 + j] = v0[j]; t[pr][h0 + 8 + j] = v1[j]; }
  }
  __syncthreads();
  {
    const int hr = tid >> 2, pq = (tid & 3) * 16;
    bf16x8 o0, o1;
#pragma unroll
    for (int j = 0; j < 8; ++j) { o0[j] = t[pq + j][hr]; o1[j] = t[pq + 8 + j][hr]; }
    *(bf16x8*)&Vth[(size_t)hr * 2048 + p0 + pq] = o0;
    *(bf16x8*)&Vth[(size_t)hr * 2048 + p0 + pq + 8] = o1;
  }
}

// ---------------- attn_flash v2: ILP-heavy, KVBLK=128 per iteration --------
// Block = 256 thr = 4 waves; all waves share the SAME 32 q-rows; kv split in
// 4 chunks (csz = ceil(P/4) to mult of 128) -> serial chain <= 4 iters/phase.
// Per wave-iteration: 16 independent K-frag loads up front (64 VGPR), 32
// MFMAs, 64 batched independent exps, ONE short chained (m,l) update per row.
// This is the structural fix for R1-R6's ~325us: the old 4-MFMA/8-load/
// chained-exp iteration (VGPR=52, no pipelining) exposed ~2.5K cyc/iter.
__global__ __launch_bounds__(256, 2) void attn_flash(
    const short* __restrict__ Q, const short* __restrict__ K,
    const short* __restrict__ Vt, float* __restrict__ ml,
    short* __restrict__ zb) {
  // LDS: pbuf 4 waves x 32x132 shorts [0, 33792); mlb [33792, 34816)
  //      zm (phase C, reuses pbuf space): 3 x 32 x 68 f32 = 26112B
  __shared__ __align__(16) char smem[34816];
  const int tid = threadIdx.x, lane = tid & 63, pc = tid >> 6;
  const int g = lane >> 4, c = lane & 15;
  const int qt = 63 - (int)blockIdx.x;   // heavy q-tiles dispatch first
  const int bi = blockIdx.y;
  const int b = bi >> 4, hd = bi & 15;
  const size_t hoff = (size_t)bi * 2048 * 64;
  const short* Qh = Q + hoff;
  const short* Kh = K + hoff;
  const short* Vth = Vt + hoff;
  short* zbh = zb + (size_t)b * 2048 * 1024 + hd * 64;

  const int qw = qt * 32;
  const int P = qw + 32;
  const int csz = ((P + 511) >> 9) << 7;   // ceil(P/4) rounded up to 128
  const int p_lo = pc * csz;
  const int p_hi = min(p_lo + csz, P);

  short* pbuf = (short*)smem + pc * 4224;  // 32 rows x pitch 132
  float* mlb  = (float*)(smem + 33792);
  float* zm   = (float*)smem;

  const bf16x8* qp0 = (const bf16x8*)&Qh[(size_t)(qw + c) * 64];
  const bf16x8* qp1 = (const bf16x8*)&Qh[(size_t)(qw + 16 + c) * 64];
  bf16x8 aq[2][2];
  aq[0][0] = qp0[g]; aq[0][1] = qp0[4 + g];
  aq[1][0] = qp1[g]; aq[1][1] = qp1[4 + g];

  // ---- phase A: partial (m,l) over this wave's chunk
  float m4[2][4], l4[2][4];
#pragma unroll
  for (int rb = 0; rb < 2; ++rb)
#pragma unroll
    for (int r = 0; r < 4; ++r) { m4[rb][r] = -1e30f; l4[rb][r] = 0.0f; }

  for (int p0 = p_lo; p0 < p_hi; p0 += 128) {
    bf16x8 k0[8], k1[8];
#pragma unroll
    for (int kb = 0; kb < 8; ++kb) {
      int row = p0 + kb * 16 + c;
      row = row < 2047 ? row : 2047;   // clamp; masked below via p<=q
      const bf16x8* kp = (const bf16x8*)&Kh[(size_t)row * 64];
      k0[kb] = kp[g]; k1[kb] = kp[4 + g];
    }
    f32x4 s[2][8];
#pragma unroll
    for (int rb = 0; rb < 2; ++rb)
#pragma unroll
      for (int kb = 0; kb < 8; ++kb) {
        f32x4 z4 = {0.0f, 0.0f, 0.0f, 0.0f};
        z4 = mfma16(aq[rb][0], k0[kb], z4);
        s[rb][kb] = mfma16(aq[rb][1], k1[kb], z4);
      }
#pragma unroll
    for (int rb = 0; rb < 2; ++rb)
#pragma unroll
      for (int r = 0; r < 4; ++r) {
        const int q = qw + rb * 16 + g * 4 + r;
        float v[8];
#pragma unroll
        for (int kb = 0; kb < 8; ++kb)
          v[kb] = (p0 + kb * 16 + c <= q) ? s[rb][kb][r] * 0.125f : -1e30f;
        const float mx = fmaxf(fmaxf(fmaxf(v[0], v[1]), fmaxf(v[2], v[3])),
                               fmaxf(fmaxf(v[4], v[5]), fmaxf(v[6], v[7])));
        const float mn = fmaxf(m4[rb][r], mx);
        float acc = l4[rb][r] * __expf(m4[rb][r] - mn);
#pragma unroll
        for (int kb = 0; kb < 8; ++kb) acc += __expf(v[kb] - mn);
        l4[rb][r] = acc; m4[rb][r] = mn;
      }
  }
  // in-wave merge across the 16 c-lanes
#pragma unroll
  for (int rb = 0; rb < 2; ++rb)
#pragma unroll
    for (int r = 0; r < 4; ++r) {
#pragma unroll
      for (int off = 1; off < 16; off <<= 1) {
        const float mo = __shfl_xor(m4[rb][r], off);
        const float lo = __shfl_xor(l4[rb][r], off);
        const float mn = fmaxf(m4[rb][r], mo);
        l4[rb][r] = l4[rb][r] * __expf(m4[rb][r] - mn) + lo * __expf(mo - mn);
        m4[rb][r] = mn;
      }
    }
  if (c == 0) {
#pragma unroll
    for (int rb = 0; rb < 2; ++rb)
#pragma unroll
      for (int r = 0; r < 4; ++r) {
        mlb[(pc * 32 + rb * 16 + g * 4 + r) * 2 + 0] = m4[rb][r];
        mlb[(pc * 32 + rb * 16 + g * 4 + r) * 2 + 1] = l4[rb][r];
      }
  }
  __syncthreads();
  // cross-chunk merge (redundant per wave)
  float M4[2][4], il[2][4];
#pragma unroll
  for (int rb = 0; rb < 2; ++rb)
#pragma unroll
    for (int r = 0; r < 4; ++r) {
      const int row = rb * 16 + g * 4 + r;
      float M = -1e30f;
#pragma unroll
      for (int j = 0; j < 4; ++j) M = fmaxf(M, mlb[(j * 32 + row) * 2 + 0]);
      float L = 0.0f;
#pragma unroll
      for (int j = 0; j < 4; ++j)
        L += mlb[(j * 32 + row) * 2 + 1] * __expf(mlb[(j * 32 + row) * 2 + 0] - M);
      M4[rb][r] = M; il[rb][r] = 1.0f / L;
    }
  if (pc == 0 && c == 0) {
#pragma unroll
    for (int rb = 0; rb < 2; ++rb)
#pragma unroll
      for (int r = 0; r < 4; ++r)
        ((float2*)ml)[(size_t)bi * 2048 + qw + rb * 16 + g * 4 + r] =
            make_float2(M4[rb][r], il[rb][r]);
  }

  // ---- phase B: recompute, P -> pbuf (bf16), PV partial
  f32x4 zacc[2][4];
#pragma unroll
  for (int rb = 0; rb < 2; ++rb)
#pragma unroll
    for (int hb = 0; hb < 4; ++hb) {
      const f32x4 z4 = {0.0f, 0.0f, 0.0f, 0.0f};
      zacc[rb][hb] = z4;
    }
  for (int p0 = p_lo; p0 < p_hi; p0 += 128) {
    bf16x8 k0[8], k1[8];
#pragma unroll
    for (int kb = 0; kb < 8; ++kb) {
      int row = p0 + kb * 16 + c;
      row = row < 2047 ? row : 2047;
      const bf16x8* kp = (const bf16x8*)&Kh[(size_t)row * 64];
      k0[kb] = kp[g]; k1[kb] = kp[4 + g];
    }
    f32x4 s[2][8];
#pragma unroll
    for (int rb = 0; rb < 2; ++rb)
#pragma unroll
      for (int kb = 0; kb < 8; ++kb) {
        f32x4 z4 = {0.0f, 0.0f, 0.0f, 0.0f};
        z4 = mfma16(aq[rb][0], k0[kb], z4);
        s[rb][kb] = mfma16(aq[rb][1], k1[kb], z4);
      }
#pragma unroll
    for (int rb = 0; rb < 2; ++rb)
#pragma unroll
      for (int kb = 0; kb < 8; ++kb)
#pragma unroll
        for (int r = 0; r < 4; ++r) {
          const int q = qw + rb * 16 + g * 4 + r;
          const int p = p0 + kb * 16 + c;
          const float e = (p <= q)
              ? __expf(__builtin_fmaf(s[rb][kb][r], 0.125f, -M4[rb][r])) * il[rb][r]
              : 0.0f;
          pbuf[(rb * 16 + g * 4 + r) * 132 + kb * 16 + c] = f2bf(e);
        }
    // PV: pa from pbuf (two 8B reads, 8B-aligned at pitch 132), bv from Vt
#pragma unroll
    for (int j = 0; j < 4; ++j) {
      const short4v p0lo = *(const short4v*)&pbuf[c * 132 + j * 32 + g * 8];
      const short4v p0hi = *(const short4v*)&pbuf[c * 132 + j * 32 + g * 8 + 4];
      const short4v p1lo = *(const short4v*)&pbuf[(16 + c) * 132 + j * 32 + g * 8];
      const short4v p1hi = *(const short4v*)&pbuf[(16 + c) * 132 + j * 32 + g * 8 + 4];
      const bf16x8 pa0 = __builtin_shufflevector(p0lo, p0hi, 0, 1, 2, 3, 4, 5, 6, 7);
      const bf16x8 pa1 = __builtin_shufflevector(p1lo, p1hi, 0, 1, 2, 3, 4, 5, 6, 7);
#pragma unroll
      for (int hb = 0; hb < 4; ++hb) {
        const bf16x8 bv =
            *(const bf16x8*)&Vth[(size_t)(hb * 16 + c) * 2048 + p0 + j * 32 + g * 8];
        zacc[0][hb] = mfma16(pa0, bv, zacc[0][hb]);
        zacc[1][hb] = mfma16(pa1, bv, zacc[1][hb]);
      }
    }
  }

  // ---- phase C: merge z partials across the 4 chunks
  __syncthreads();  // pbuf dead everywhere; zm reuses its space
  if (pc != 0) {
#pragma unroll
    for (int rb = 0; rb < 2; ++rb)
#pragma unroll
      for (int hb = 0; hb < 4; ++hb)
#pragma unroll
        for (int r = 0; r < 4; ++r)
          zm[((pc - 1) * 32 + rb * 16 + g * 4 + r) * 68 + hb * 16 + c] = zacc[rb][hb][r];
  }
  __syncthreads();
  if (pc == 0) {
#pragma unroll
    for (int rb = 0; rb < 2; ++rb)
#pragma unroll
      for (int hb = 0; hb < 4; ++hb)
#pragma unroll
        for (int r = 0; r < 4; ++r) {
          float z = zacc[rb][hb][r];
#pragma unroll
          for (int j = 0; j < 3; ++j)
            z += zm[(j * 32 + rb * 16 + g * 4 + r) * 68 + hb * 16 + c];
          zbh[(size_t)(qw + rb * 16 + g * 4 + r) * 1024 + hb * 16 + c] = f2bf(z);
        }
  }
}

// ---------------- att_write: materialize att, massively parallel -----------
__global__ __launch_bounds__(256) void att_write(
    const short* __restrict__ Q, const short* __restrict__ K,
    const float* __restrict__ ml, float* __restrict__ att) {
  __shared__ float fbuf_s[4][16 * 36];
  const int tid = threadIdx.x, lane = tid & 63, wave = tid >> 6;
  const int g = lane >> 4, c = lane & 15;
  const int qt = blockIdx.x, pt = blockIdx.y, bi = blockIdx.z;
  const int qs = wave >> 1, ph = wave & 1;
  const int qw = qt * 32 + qs * 16;
  const int pb = pt * 256 + ph * 128;
  float* atth = att + (size_t)bi * 2048 * 2048;
  const int r0 = lane >> 3, c4 = (lane & 7) * 4;

  if (pb > qw + 15) {  // strip entirely above the diagonal: pure zeros
    const f32x4 zf = {0.0f, 0.0f, 0.0f, 0.0f};
#pragma unroll
    for (int j = 0; j < 4; ++j) {
      __builtin_nontemporal_store(zf, (f32x4*)&atth[(size_t)(qw + r0) * 2048 + pb + j * 32 + c4]);
      __builtin_nontemporal_store(zf, (f32x4*)&atth[(size_t)(qw + 8 + r0) * 2048 + pb + j * 32 + c4]);
    }
    return;
  }

  const size_t hoff = (size_t)bi * 2048 * 64;
  const short* Qh = Q + hoff;
  const short* Kh = K + hoff;
  const bf16x8* qp = (const bf16x8*)&Qh[(size_t)(qw + c) * 64];
  const bf16x8 aq0 = qp[g], aq1 = qp[4 + g];
  float m4[4], il[4];
#pragma unroll
  for (int r = 0; r < 4; ++r) {
    const float2 t = ((const float2*)ml)[(size_t)bi * 2048 + qw + g * 4 + r];
    m4[r] = t.x; il[r] = t.y;
  }
  float* fbuf = fbuf_s[wave];
  for (int p0 = pb; p0 < pb + 128; p0 += 32) {
    const bf16x8* kp0 = (const bf16x8*)&Kh[(size_t)(p0 + c) * 64];
    const bf16x8* kp1 = (const bf16x8*)&Kh[(size_t)(p0 + 16 + c) * 64];
    f32x4 s0 = {0.0f, 0.0f, 0.0f, 0.0f}, s1 = {0.0f, 0.0f, 0.0f, 0.0f};
    s0 = mfma16(aq0, kp0[g], s0);
    s0 = mfma16(aq1, kp0[4 + g], s0);
    s1 = mfma16(aq0, kp1[g], s1);
    s1 = mfma16(aq1, kp1[4 + g], s1);
#pragma unroll
    for (int f = 0; f < 2; ++f) {
      const f32x4& ss = f ? s1 : s0;
#pragma unroll
      for (int r = 0; r < 4; ++r) {
        const int q = qw + g * 4 + r, p = p0 + f * 16 + c;
        const float e = (p <= q) ? __expf(ss[r] * 0.125f - m4[r]) * il[r] : 0.0f;
        fbuf[(g * 4 + r) * 36 + f * 16 + c] = e;
      }
    }
    const f32x4 v0 = *(const f32x4*)&fbuf[r0 * 36 + c4];
    const f32x4 v1 = *(const f32x4*)&fbuf[(8 + r0) * 36 + c4];
    __builtin_nontemporal_store(v0, (f32x4*)&atth[(size_t)(qw + r0) * 2048 + p0 + c4]);
    __builtin_nontemporal_store(v1, (f32x4*)&atth[(size_t)(qw + 8 + r0) * 2048 + p0 + c4]);
  }
}

// ---------------- launch ----------------
extern "C" void kernel_launch(void* const* d_in, const int* in_sizes, int n_in,
                              void* d_out, int out_size, void* d_ws, size_t ws_size,
                              hipStream_t stream) {
  (void)in_sizes; (void)n_in; (void)out_size; (void)ws_size;
  const float* x    = (const float*)d_in[0];
  const float* WQ   = (const float*)d_in[1];
  const float* WK   = (const float*)d_in[2];
  const float* WV   = (const float*)d_in[3];
  const float* WO   = (const float*)d_in[4];
  const float* lnaw = (const float*)d_in[5];
  const float* lnab = (const float*)d_in[6];
  const float* lnmw = (const float*)d_in[7];
  const float* lnmb = (const float*)d_in[8];
  const float* w1   = (const float*)d_in[9];
  const float* b1   = (const float*)d_in[10];
  const float* w2   = (const float*)d_in[11];
  const float* b2   = (const float*)d_in[12];

  char* ws = (char*)d_ws;
  const size_t MB = 1024 * 1024;
  short* Wqb  = (short*)(ws + 0 * MB);   // 2MB
  short* Wkb  = (short*)(ws + 2 * MB);   // 2MB
  short* Wvb  = (short*)(ws + 4 * MB);   // 2MB
  short* Wob  = (short*)(ws + 6 * MB);   // 2MB
  short* w1b  = (short*)(ws + 8 * MB);   // 8MB
  short* w2b  = (short*)(ws + 16 * MB);  // 8MB
  short* yb   = (short*)(ws + 24 * MB);  // 8MB (LN1 out; reused for LN2 out)
  short* Qb   = (short*)(ws + 32 * MB);  // 8MB
  short* Kb   = (short*)(ws + 40 * MB);  // 8MB
  short* Vb   = (short*)(ws + 48 * MB);  // 8MB
  short* Vtb  = (short*)(ws + 56 * MB);  // 8MB
  short* zbuf = (short*)(ws + 64 * MB);  // 8MB
  float* x1   = (float*)(ws + 72 * MB);  // 16MB (written AFTER att_write)
  float* mlw  = (float*)(ws + 72 * MB);  // 512KB, overlaps x1: ml consumed by
                                         // att_write BEFORE gemm<1> writes x1
  short* hb   = (short*)(ws + 32 * MB);  // 32MB, reuses Q/K/V/Vt (dead by MLP1)

  float* outx = (float*)d_out;
  float* att  = outx + (size_t)2 * 2048 * 1024;  // output 1 region

  // weight converts (fp32 -> bf16)
  cvt_bf16<<<dim3(1024), dim3(256), 0, stream>>>(WQ, Wqb, 262144);
  cvt_bf16<<<dim3(1024), dim3(256), 0, stream>>>(WK, Wkb, 262144);
  cvt_bf16<<<dim3(1024), dim3(256), 0, stream>>>(WV, Wvb, 262144);
  cvt_wo<<<dim3(4096), dim3(256), 0, stream>>>(WO, Wob);
  cvt_bf16<<<dim3(4096), dim3(256), 0, stream>>>(w1, w1b, 1048576);
  cvt_bf16<<<dim3(4096), dim3(256), 0, stream>>>(w2, w2b, 1048576);

  // LN1
  ln_kernel<<<dim3(4096), dim3(256), 0, stream>>>(x, lnaw, lnab, yb);

  // QKV projections (scatter to [B,H,S,DH])
  gemm_bf16k<0><<<dim3(8, 32), dim3(256), 0, stream>>>(yb, Wqb, nullptr, Qb, nullptr, nullptr, 4096, 1024, 1024);
  gemm_bf16k<0><<<dim3(8, 32), dim3(256), 0, stream>>>(yb, Wkb, nullptr, Kb, nullptr, nullptr, 4096, 1024, 1024);
  gemm_bf16k<0><<<dim3(8, 32), dim3(256), 0, stream>>>(yb, Wvb, nullptr, Vb, nullptr, nullptr, 4096, 1024, 1024);

  // V transpose for PV B-operand
  transpose_v<<<dim3(32, 32), dim3(256), 0, stream>>>(Vb, Vtb);

  // attention stats + z (no att materialization)
  attn_flash<<<dim3(64, 32), dim3(256), 0, stream>>>(Qb, Kb, Vtb, mlw, zbuf);

  // att materialization (embarrassingly parallel, store-BW-bound)
  att_write<<<dim3(64, 8, 32), dim3(256), 0, stream>>>(Qb, Kb, mlw, att);

  // output projection + residual -> x1 (fp32)
  gemm_bf16k<1><<<dim3(8, 32), dim3(256), 0, stream>>>(zbuf, Wob, x1, nullptr, x, nullptr, 4096, 1024, 1024);

  // LN2
  ln_kernel<<<dim3(4096), dim3(256), 0, stream>>>(x1, lnmw, lnmb, yb);

  // MLP
  gemm_bf16k<2><<<dim3(32, 32), dim3(256), 0, stream>>>(yb, w1b, nullptr, hb, nullptr, b1, 4096, 4096, 1024);
  gemm_bf16k<3><<<dim3(8, 32), dim3(256), 0, stream>>>(hb, w2b, outx, nullptr, x1, b2, 4096, 1024, 4096);
}